// Round 5
// baseline (3433.593 us; speedup 1.0000x reference)
//
#include <hip/hip_runtime.h>
#include <cstdint>
#include <cstddef>

#define NN   50000
#define NE   400000
#define FDIM 256
#define HDIM 512
#define CDIM 3
#define NBLK 6

typedef __attribute__((ext_vector_type(4))) float f4;
typedef __attribute__((ext_vector_type(4))) float f32x4;
typedef _Float16 half8 __attribute__((ext_vector_type(8)));
typedef _Float16 half4 __attribute__((ext_vector_type(4)));

template <typename T>
__device__ inline void nt_store(T* p, T v) { __builtin_nontemporal_store(v, p); }

// ---------------- setup kernels ----------------

__global__ __launch_bounds__(256) void k_zero_i32(int* p, int n) {
  int i = blockIdx.x * 256 + threadIdx.x;
  if (i < n) p[i] = 0;
}

__global__ __launch_bounds__(256) void k_hist(const int* __restrict__ dst, int* __restrict__ cnt) {
  int e = blockIdx.x * 256 + threadIdx.x;
  if (e < NE) {
    int d = dst[e];
    if ((unsigned)d < (unsigned)NN) atomicAdd(&cnt[d], 1);
  }
}

__global__ __launch_bounds__(256) void k_dinv(const int* __restrict__ cnt, float* __restrict__ dinv) {
  int i = blockIdx.x * 256 + threadIdx.x;
  if (i < NN) dinv[i] = rsqrtf((float)cnt[i] + 1.0f);
}

// single-block exclusive scan of cnt[NN] -> row_start[NN+1]
__global__ __launch_bounds__(1024) void k_scan(const int* __restrict__ cnt, int* __restrict__ row_start) {
  __shared__ int wsum[16];
  __shared__ int carry_s;
  int tid = threadIdx.x, lane = tid & 63, wid = tid >> 6;
  if (tid == 0) carry_s = 0;
  __syncthreads();
  for (int base = 0; base < NN; base += 1024) {
    int i = base + tid;
    int v = (i < NN) ? cnt[i] : 0;
    int incl = v;
#pragma unroll
    for (int off = 1; off < 64; off <<= 1) {
      int t = __shfl_up(incl, off);
      if (lane >= off) incl += t;
    }
    if (lane == 63) wsum[wid] = incl;
    __syncthreads();
    int woff = 0;
    for (int w = 0; w < wid; ++w) woff += wsum[w];
    int excl = carry_s + woff + (incl - v);
    if (i < NN) row_start[i] = excl;
    __syncthreads();
    if (tid == 1023) carry_s = excl + v;
    __syncthreads();
  }
  if (threadIdx.x == 0) row_start[NN] = carry_s;
}

__global__ __launch_bounds__(256) void k_fill(const int* __restrict__ src, const int* __restrict__ dst,
    const int* __restrict__ row_start, int* __restrict__ fill,
    const float* __restrict__ dinv, int* __restrict__ csr_src, float* __restrict__ csr_coef) {
  int e = blockIdx.x * 256 + threadIdx.x;
  if (e >= NE) return;
  int s = src[e], d = dst[e];
  if ((unsigned)s >= (unsigned)NN || (unsigned)d >= (unsigned)NN) return;
  int pos = row_start[d] + atomicAdd(&fill[d], 1);
  csr_src[pos] = s;
  csr_coef[pos] = dinv[s] * dinv[d];
}

// ---------------- conversion kernels ----------------

// x [N,256] fp32 -> hi/lo fp16 (no relu, no transpose)
__global__ __launch_bounds__(256) void k_cvt_x(const float* __restrict__ x,
    _Float16* __restrict__ xhi, _Float16* __restrict__ xlo, int n4) {
  int i = blockIdx.x * 256 + threadIdx.x;
  if (i >= n4) return;
  f4 v = ((const f4*)x)[i];
  half4 h, l;
#pragma unroll
  for (int c = 0; c < 4; ++c) {
    float vv = v[c];
    _Float16 hh = (_Float16)vv;
    h[c] = hh;
    l[c] = (_Float16)(vv - (float)hh);
  }
  ((half4*)xhi)[i] = h;
  ((half4*)xlo)[i] = l;
}

// W [K,N] fp32 -> transposed hi/lo fp16 [N,K]  (z = matrix index)
__global__ __launch_bounds__(256) void k_cvt_wt(const float* __restrict__ W,
    _Float16* __restrict__ Whi, _Float16* __restrict__ Wlo, int K, int N) {
  __shared__ float tile[32][33];
  int l = blockIdx.z;
  const float* Wl = W + (size_t)l * K * N;
  _Float16* Oh = Whi + (size_t)l * K * N;
  _Float16* Ol = Wlo + (size_t)l * K * N;
  int k0 = blockIdx.x * 32, n0 = blockIdx.y * 32;
  int tx = threadIdx.x & 31, ty = threadIdx.x >> 5;
#pragma unroll
  for (int p = 0; p < 4; ++p)
    tile[ty + 8 * p][tx] = Wl[(size_t)(k0 + ty + 8 * p) * N + n0 + tx];
  __syncthreads();
#pragma unroll
  for (int p = 0; p < 4; ++p) {
    int n = n0 + ty + 8 * p, k = k0 + tx;
    float v = tile[tx][ty + 8 * p];
    _Float16 hi = (_Float16)v;
    Oh[(size_t)n * K + k] = hi;
    Ol[(size_t)n * K + k] = (_Float16)(v - (float)hi);
  }
}

// ---------------- MFMA GEMM: C[M,512] = (Ahi+Alo)[M,K] @ (Bhi+Blo)^T ----------------
// A: [M,K] fp16 hi/lo; B: [N,K] fp16 hi/lo (pre-transposed, k-contiguous)
// fp32-accurate via 3-term split: ah*bh + ah*bl + al*bh
// XCD swizzle: 4 column-tiles of one A row-block land consecutively on one XCD.

#define LDK 40  // 32 + 8 pad: b128 frag reads land 2-way/bank (free)

__global__ __launch_bounds__(256) void k_gemm16(
    const _Float16* __restrict__ Ahi, const _Float16* __restrict__ Alo,
    const _Float16* __restrict__ Bhi, const _Float16* __restrict__ Blo,
    float* __restrict__ C, int M, int K) {
  const int nrb = (M + 127) >> 7;         // row blocks (391)
  const int rpx = (nrb + 7) >> 3;         // row blocks per XCD (49)
  const int f = blockIdx.x;
  const int q = f & 7, s = f >> 3;
  const int rb = q * rpx + (s >> 2);
  const int cb = s & 3;
  if (rb >= nrb) return;
  const int row0 = rb * 128, col0 = cb * 128;

  __shared__ _Float16 As[2][128][LDK];
  __shared__ _Float16 Bs[2][128][LDK];
  const int tid = threadIdx.x;
  const int lane = tid & 63, wave = tid >> 6;
  const int wm = wave & 1, wn = wave >> 1;
  const int quad = lane >> 4, r = lane & 15;

  f32x4 acc[4][4];
#pragma unroll
  for (int i = 0; i < 4; ++i)
#pragma unroll
    for (int j = 0; j < 4; ++j) acc[i][j] = (f32x4){0.f, 0.f, 0.f, 0.f};

  for (int k0 = 0; k0 < K; k0 += 32) {
    // stage A & B tiles (hi + lo) : 128 rows x 32 k each
#pragma unroll
    for (int j = 0; j < 2; ++j) {
      int c = tid + j * 256;
      int rrow = c >> 2, kc = (c & 3) * 8;
      int grow = row0 + rrow;
      half8 vh = {}, vl = {};
      if (grow < M) {
        vh = *(const half8*)(Ahi + (size_t)grow * K + k0 + kc);
        vl = *(const half8*)(Alo + (size_t)grow * K + k0 + kc);
      }
      *(half8*)&As[0][rrow][kc] = vh;
      *(half8*)&As[1][rrow][kc] = vl;
      int gn = col0 + rrow;
      *(half8*)&Bs[0][rrow][kc] = *(const half8*)(Bhi + (size_t)gn * K + k0 + kc);
      *(half8*)&Bs[1][rrow][kc] = *(const half8*)(Blo + (size_t)gn * K + k0 + kc);
    }
    __syncthreads();

    half8 ah[4], al[4], bh[4], bl[4];
#pragma unroll
    for (int mi = 0; mi < 4; ++mi) {
      int mrow = wm * 64 + mi * 16 + r;
      ah[mi] = *(const half8*)&As[0][mrow][quad * 8];
      al[mi] = *(const half8*)&As[1][mrow][quad * 8];
    }
#pragma unroll
    for (int ni = 0; ni < 4; ++ni) {
      int nrow = wn * 64 + ni * 16 + r;
      bh[ni] = *(const half8*)&Bs[0][nrow][quad * 8];
      bl[ni] = *(const half8*)&Bs[1][nrow][quad * 8];
    }
#pragma unroll
    for (int mi = 0; mi < 4; ++mi)
#pragma unroll
      for (int ni = 0; ni < 4; ++ni) {
        acc[mi][ni] = __builtin_amdgcn_mfma_f32_16x16x32_f16(ah[mi], bh[ni], acc[mi][ni], 0, 0, 0);
        acc[mi][ni] = __builtin_amdgcn_mfma_f32_16x16x32_f16(ah[mi], bl[ni], acc[mi][ni], 0, 0, 0);
        acc[mi][ni] = __builtin_amdgcn_mfma_f32_16x16x32_f16(al[mi], bh[ni], acc[mi][ni], 0, 0, 0);
      }
    __syncthreads();
  }

  // epilogue: C/D layout col=lane&15, row=quad*4+reg
#pragma unroll
  for (int mi = 0; mi < 4; ++mi)
#pragma unroll
    for (int reg = 0; reg < 4; ++reg) {
      int grow = row0 + wm * 64 + mi * 16 + quad * 4 + reg;
      if (grow < M) {
#pragma unroll
        for (int ni = 0; ni < 4; ++ni)
          nt_store(&C[(size_t)grow * HDIM + col0 + wn * 64 + ni * 16 + r], acc[mi][ni][reg]);
      }
    }
}

// ---------------- CSR aggregation ----------------
// One wave per node, lane covers 8 features (full 512-feat row per wave).
// 4-edge unroll -> 8 independent 16B gathers in flight per thread.
// Writes: one 16B half8 store per array per thread (full EA write granularity;
// the old 8B half4 stores showed WRITE_SIZE = 2x logical).

__global__ __launch_bounds__(256) void k_agg(const float* __restrict__ h,
    _Float16* __restrict__ xhi, _Float16* __restrict__ xlo, float* __restrict__ xf,
    const int* __restrict__ row_start, const int* __restrict__ csr_src,
    const float* __restrict__ csr_coef, const float* __restrict__ dinv,
    const float* __restrict__ bias) {
  int wid = threadIdx.x >> 6, lane = threadIdx.x & 63;
  int i = blockIdx.x * 4 + wid;
  if (i >= NN) return;
  int c = lane * 8;
  float di = dinv[i];
  float d2 = di * di;
  const float* hi_ = h + (size_t)i * HDIM + c;
  f4 aA = *(const f4*)hi_ * d2;
  f4 aB = *(const f4*)(hi_ + 4) * d2;
  f4 bA = {0.f, 0.f, 0.f, 0.f}, bB = bA;
  int e0 = row_start[i], e1 = row_start[i + 1];
  int e = e0;
  for (; e + 4 <= e1; e += 4) {
    int s0 = csr_src[e], s1 = csr_src[e + 1], s2 = csr_src[e + 2], s3 = csr_src[e + 3];
    float c0 = csr_coef[e], c1 = csr_coef[e + 1], c2 = csr_coef[e + 2], c3 = csr_coef[e + 3];
    const float* p0 = h + (size_t)s0 * HDIM + c;
    const float* p1 = h + (size_t)s1 * HDIM + c;
    const float* p2 = h + (size_t)s2 * HDIM + c;
    const float* p3 = h + (size_t)s3 * HDIM + c;
    f4 r0A = *(const f4*)p0, r0B = *(const f4*)(p0 + 4);
    f4 r1A = *(const f4*)p1, r1B = *(const f4*)(p1 + 4);
    f4 r2A = *(const f4*)p2, r2B = *(const f4*)(p2 + 4);
    f4 r3A = *(const f4*)p3, r3B = *(const f4*)(p3 + 4);
    aA += r0A * c0; aB += r0B * c0;
    bA += r1A * c1; bB += r1B * c1;
    aA += r2A * c2; aB += r2B * c2;
    bA += r3A * c3; bB += r3B * c3;
  }
  for (; e < e1; ++e) {
    int s = csr_src[e];
    float cf = csr_coef[e];
    const float* p = h + (size_t)s * HDIM + c;
    aA += *(const f4*)p * cf;
    aB += *(const f4*)(p + 4) * cf;
  }
  f4 accA = aA + bA, accB = aB + bB;
  accA += *(const f4*)(bias + c);
  accB += *(const f4*)(bias + c + 4);
#pragma unroll
  for (int q = 0; q < 4; ++q) { accA[q] = fmaxf(accA[q], 0.f); accB[q] = fmaxf(accB[q], 0.f); }
  half8 hh, ll;
#pragma unroll
  for (int q = 0; q < 4; ++q) {
    _Float16 hv = (_Float16)accA[q];
    hh[q] = hv; ll[q] = (_Float16)(accA[q] - (float)hv);
    _Float16 hv2 = (_Float16)accB[q];
    hh[q + 4] = hv2; ll[q + 4] = (_Float16)(accB[q] - (float)hv2);
  }
  nt_store((half8*)(xhi + (size_t)i * HDIM + c), hh);
  nt_store((half8*)(xlo + (size_t)i * HDIM + c), ll);
  if (xf) {
    nt_store((f4*)(xf + (size_t)i * HDIM + c), accA);
    nt_store((f4*)(xf + (size_t)i * HDIM + c + 4), accB);
  }
}

// final conv: h3[N,3] = X[N,512] @ W1[512,3]; one wave per node
__global__ __launch_bounds__(256) void k_gemm3(const float* __restrict__ X, const float* __restrict__ W1,
    float* __restrict__ h3) {
  int wid = threadIdx.x >> 6, lane = threadIdx.x & 63;
  int i = blockIdx.x * 4 + wid;
  if (i >= NN) return;
  const float* xi = X + (size_t)i * HDIM;
  float a0 = 0.f, a1 = 0.f, a2 = 0.f;
#pragma unroll
  for (int t = 0; t < HDIM / 64; ++t) {
    int k = t * 64 + lane;
    float v = xi[k];
    a0 = fmaf(v, W1[k * 3 + 0], a0);
    a1 = fmaf(v, W1[k * 3 + 1], a1);
    a2 = fmaf(v, W1[k * 3 + 2], a2);
  }
#pragma unroll
  for (int off = 32; off > 0; off >>= 1) {
    a0 += __shfl_down(a0, off);
    a1 += __shfl_down(a1, off);
    a2 += __shfl_down(a2, off);
  }
  if (lane == 0) {
    h3[(size_t)i * 3 + 0] = a0;
    h3[(size_t)i * 3 + 1] = a1;
    h3[(size_t)i * 3 + 2] = a2;
  }
}

__global__ __launch_bounds__(256) void k_agg3(const float* __restrict__ h3, float* __restrict__ out,
    const int* __restrict__ row_start, const int* __restrict__ csr_src,
    const float* __restrict__ csr_coef, const float* __restrict__ dinv,
    const float* __restrict__ b1) {
  int i = blockIdx.x * 256 + threadIdx.x;
  if (i >= NN) return;
  float d2 = dinv[i] * dinv[i];
  float o0 = h3[(size_t)i * 3 + 0] * d2;
  float o1 = h3[(size_t)i * 3 + 1] * d2;
  float o2 = h3[(size_t)i * 3 + 2] * d2;
  int e0 = row_start[i], e1 = row_start[i + 1];
  for (int e = e0; e < e1; ++e) {
    int s = csr_src[e];
    float c = csr_coef[e];
    o0 = fmaf(c, h3[(size_t)s * 3 + 0], o0);
    o1 = fmaf(c, h3[(size_t)s * 3 + 1], o1);
    o2 = fmaf(c, h3[(size_t)s * 3 + 2], o2);
  }
  out[(size_t)i * 3 + 0] = o0 + b1[0];
  out[(size_t)i * 3 + 1] = o1 + b1[1];
  out[(size_t)i * 3 + 2] = o2 + b1[2];
}

// ---------------- launch ----------------

extern "C" void kernel_launch(void* const* d_in, const int* in_sizes, int n_in,
                              void* d_out, int out_size, void* d_ws, size_t ws_size,
                              hipStream_t stream) {
  const float* x  = (const float*)d_in[0];
  const int*   ei = (const int*)d_in[1];
  const float* W0 = (const float*)d_in[2];
  const float* b0 = (const float*)d_in[3];
  const float* Wr = (const float*)d_in[4];
  const float* br = (const float*)d_in[5];
  const float* W1 = (const float*)d_in[6];
  const float* b1 = (const float*)d_in[7];
  float* out = (float*)d_out;
  float* X = out + (size_t)NN * CDIM;  // final relu'd state [NN, HDIM] == output 1

  char* ws = (char*)d_ws;
  size_t off = 0;
  auto alloc = [&](size_t bytes) -> void* {
    void* p = ws + off;
    off = (off + bytes + 255) & ~(size_t)255;
    return p;
  };
  float*     Y      = (float*)alloc((size_t)NN * HDIM * 4);        // 102.4 MB
  _Float16*  Xhi    = (_Float16*)alloc((size_t)NN * HDIM * 2);     // 51.2 MB
  _Float16*  Xlo    = (_Float16*)alloc((size_t)NN * HDIM * 2);     // 51.2 MB
  _Float16*  W0thi  = (_Float16*)alloc((size_t)FDIM * HDIM * 2);
  _Float16*  W0tlo  = (_Float16*)alloc((size_t)FDIM * HDIM * 2);
  _Float16*  Wrthi  = (_Float16*)alloc((size_t)NBLK * 2 * HDIM * HDIM * 2);
  _Float16*  Wrtlo  = (_Float16*)alloc((size_t)NBLK * 2 * HDIM * HDIM * 2);
  float*     csr_coef = (float*)alloc((size_t)NE * 4);
  float*     dinv     = (float*)alloc((size_t)NN * 4);
  float*     h3       = (float*)alloc((size_t)NN * CDIM * 4);
  int*       cnt      = (int*)alloc((size_t)NN * 4);
  int*       fill     = (int*)alloc((size_t)NN * 4);
  int*       row_start= (int*)alloc((size_t)(NN + 1) * 4);
  int*       csr_src  = (int*)alloc((size_t)NE * 4);

  const int* src = ei;
  const int* dst = ei + NE;

  // ---- setup (once per call; reused by all 14 layers) ----
  k_zero_i32<<<(NN + 255) / 256, 256, 0, stream>>>(cnt, NN);
  k_zero_i32<<<(NN + 255) / 256, 256, 0, stream>>>(fill, NN);
  k_hist<<<(NE + 255) / 256, 256, 0, stream>>>(dst, cnt);
  k_dinv<<<(NN + 255) / 256, 256, 0, stream>>>(cnt, dinv);
  k_scan<<<1, 1024, 0, stream>>>(cnt, row_start);
  k_fill<<<(NE + 255) / 256, 256, 0, stream>>>(src, dst, row_start, fill, dinv, csr_src, csr_coef);

  // weight + input conversion (hi/lo fp16, weights transposed to [N][K])
  k_cvt_x<<<(NN * FDIM / 4 + 255) / 256, 256, 0, stream>>>(x, Xhi, Xlo, NN * FDIM / 4);
  {
    dim3 g0(FDIM / 32, HDIM / 32, 1);
    k_cvt_wt<<<g0, 256, 0, stream>>>(W0, W0thi, W0tlo, FDIM, HDIM);
    dim3 gr(HDIM / 32, HDIM / 32, NBLK * 2);
    k_cvt_wt<<<gr, 256, 0, stream>>>(Wr, Wrthi, Wrtlo, HDIM, HDIM);
  }

  const int nrb = (NN + 127) / 128;          // 391 row blocks
  const int rpx = (nrb + 7) / 8;             // 49 per XCD
  const int gemm_blocks = 8 * rpx * 4;       // 1568 (XCD-swizzled 1D grid)
  const int agg_grid = (NN + 3) / 4;         // one wave per node, full row

  // conv0: (x0 hi/lo live in the head of Xhi/Xlo; consumed before agg overwrites)
  k_gemm16<<<gemm_blocks, 256, 0, stream>>>(Xhi, Xlo, W0thi, W0tlo, Y, NN, FDIM);
  k_agg<<<agg_grid, 256, 0, stream>>>(Y, Xhi, Xlo, nullptr, row_start, csr_src, csr_coef, dinv, b0);

  // 6 residual blocks x 2 convs, all H->H
  for (int ib = 0; ib < NBLK; ++ib) {
    for (int j = 0; j < 2; ++j) {
      int li = ib * 2 + j;
      const _Float16* Wh = Wrthi + (size_t)li * HDIM * HDIM;
      const _Float16* Wl = Wrtlo + (size_t)li * HDIM * HDIM;
      const float* bb = br + (size_t)li * HDIM;
      bool last = (ib == NBLK - 1) && (j == 1);
      k_gemm16<<<gemm_blocks, 256, 0, stream>>>(Xhi, Xlo, Wh, Wl, Y, NN, HDIM);
      k_agg<<<agg_grid, 256, 0, stream>>>(Y, Xhi, Xlo, last ? X : nullptr,
                                          row_start, csr_src, csr_coef, dinv, bb);
    }
  }

  // final conv: X (relu'd, fp32) @ W1 -> out[N,3]
  k_gemm3<<<(NN + 3) / 4, 256, 0, stream>>>(X, W1, h3);
  k_agg3<<<(NN + 255) / 256, 256, 0, stream>>>(h3, out, row_start, csr_src, csr_coef, dinv, b1);
}